// Round 11
// baseline (233.086 us; speedup 1.0000x reference)
//
#include <hip/hip_runtime.h>

// ---------- types ----------
using bf16x8 = __attribute__((ext_vector_type(8))) __bf16;
using f32x4  = __attribute__((ext_vector_type(4))) float;

__device__ __forceinline__ short f2bf(float f) {
  unsigned u = __builtin_bit_cast(unsigned, f);
  u += 0x7fffu + ((u >> 16) & 1u);   // RNE
  return (short)(u >> 16);
}

// async global->LDS, 16B per lane; lds base must be wave-uniform
__device__ __forceinline__ void gll16(const void* g, void* l) {
  __builtin_amdgcn_global_load_lds((const __attribute__((address_space(1))) unsigned*)g,
                                   (__attribute__((address_space(3))) unsigned*)l, 16, 0, 0);
}

// ---------- fused preprocessing: x->bf16 + all 3 weight transposes ----------
// grid 6656: [0,4096) convert x; [4096,5120) Wq; [5120,5632) Wkv; [5632,6656) Wo
__global__ __launch_bounds__(256) void fused_pre(const float* __restrict__ x,
                                                 const float* __restrict__ Wq,
                                                 const float* __restrict__ Wkv,
                                                 const float* __restrict__ Wo,
                                                 short* __restrict__ xb,
                                                 short* __restrict__ Wqkvt,
                                                 short* __restrict__ Wot) {
  const int bx = blockIdx.x, tid = threadIdx.x;
  if (bx < 4096) {
    int i = (bx * 256 + tid) * 4;
    float4 f = *(const float4*)(&x[i]);
    short4 o;
    o.x = f2bf(f.x); o.y = f2bf(f.y); o.z = f2bf(f.z); o.w = f2bf(f.w);
    *(short4*)(&xb[i]) = o;
    return;
  }
  __shared__ short tile[32][33];
  const float* src; short* dst; int C, ti;
  if (bx < 5120)      { src = Wq;  dst = Wqkvt;               C = 1024; ti = bx - 4096; }
  else if (bx < 5632) { src = Wkv; dst = Wqkvt + 1024 * 1024; C = 512;  ti = bx - 5120; }
  else                { src = Wo;  dst = Wot;                 C = 1024; ti = bx - 5632; }
  int ctiles = C >> 5;
  int c0 = (ti % ctiles) * 32, r0 = (ti / ctiles) * 32;
  int tx = tid & 31, ty = tid >> 5;
  for (int i = ty; i < 32; i += 8)
    tile[i][tx] = f2bf(src[(r0 + i) * C + c0 + tx]);
  __syncthreads();
  for (int i = ty; i < 32; i += 8)
    dst[(c0 + i) * 1024L + r0 + tx] = tile[tx][i];
}

// ---------- bf16 MFMA GEMM: C[M][N] = A[M][K] * Bt[N][K]^T ----------
// R10 config (measured best): block 64 x 32*NT, BK=64, dbuf gll16,
// XOR-swizzled LDS, grid 1024 = 4 blocks/CU, compile-time N/K full unroll.
template <int N, int K, int NT, bool OUT_BF16, bool WRITE_VT>
__global__ __launch_bounds__(256) void gemm_bt(const short* __restrict__ A,
                                               const short* __restrict__ Bt,
                                               void* __restrict__ Cout,
                                               short* __restrict__ Vt) {
  __shared__ __attribute__((aligned(16))) short sA[2][64 * 64];
  __shared__ __attribute__((aligned(16))) short sB[2][32 * NT * 64];
  const int tid  = threadIdx.x;
  const int bm   = blockIdx.y * 64, bn = blockIdx.x * (32 * NT);
  const int wave = tid >> 6, lane = tid & 63;
  const int wm = (wave >> 1) * 32, wn = (wave & 1) * (16 * NT);
  const int qd = lane >> 4, c16 = lane & 15;

  f32x4 acc[2][NT] = {};

  auto stage = [&](int it, int d) {
    int k0 = it * 64;
#pragma unroll
    for (int i = 0; i < 2; i++) {           // A: 64 rows x 8 octets
      int c = i * 256 + tid;
      int r = c >> 3, cc = c & 7;
      gll16(&A[(bm + r) * (long)K + k0 + ((cc ^ (r & 7)) * 8)],
            &sA[d][(i * 256 + wave * 64) * 8]);
    }
#pragma unroll
    for (int i = 0; i < NT; i++) {          // B: 32*NT rows x 8 octets
      int c = i * 256 + tid;
      int r = c >> 3, cc = c & 7;
      gll16(&Bt[(bn + r) * (long)K + k0 + ((cc ^ (r & 7)) * 8)],
            &sB[d][(i * 256 + wave * 64) * 8]);
    }
  };

  constexpr int niter = K >> 6;             // 16 — compile-time, fully unrolled
  stage(0, 0);
#pragma unroll
  for (int it = 0; it < niter; it++) {
    const int cur = it & 1;
    asm volatile("" ::: "memory");
    __builtin_amdgcn_s_barrier();            // buf[cur^1] free
    if (it + 1 < niter) {
      stage(it + 1, cur ^ 1);                // 2+NT gll16/thread
      if constexpr (NT == 3) asm volatile("s_waitcnt vmcnt(5)" ::: "memory");
      else                   asm volatile("s_waitcnt vmcnt(4)" ::: "memory");
    } else {
      asm volatile("s_waitcnt vmcnt(0)" ::: "memory");
    }
    __builtin_amdgcn_s_barrier();            // cur data visible
    asm volatile("" ::: "memory");

    bf16x8 af[2][2], bfr[NT][2];
#pragma unroll
    for (int mt = 0; mt < 2; mt++) {
      int rr = wm + mt * 16 + c16;
#pragma unroll
      for (int ks = 0; ks < 2; ks++)
        af[mt][ks] = *(const bf16x8*)(&sA[cur][rr * 64 + (((ks * 4 + qd) ^ (rr & 7)) * 8)]);
    }
#pragma unroll
    for (int nt = 0; nt < NT; nt++) {
      int rr = wn + nt * 16 + c16;
#pragma unroll
      for (int ks = 0; ks < 2; ks++)
        bfr[nt][ks] = *(const bf16x8*)(&sB[cur][rr * 64 + (((ks * 4 + qd) ^ (rr & 7)) * 8)]);
    }
#pragma unroll
    for (int ks = 0; ks < 2; ks++)
#pragma unroll
      for (int mt = 0; mt < 2; mt++)
#pragma unroll
        for (int nt = 0; nt < NT; nt++)
          acc[mt][nt] = __builtin_amdgcn_mfma_f32_16x16x32_bf16(af[mt][ks], bfr[nt][ks],
                                                                acc[mt][nt], 0, 0, 0);
  }

  // epilogue: C/D layout col=lane&15, row=(lane>>4)*4+reg  [m89-verified]
#pragma unroll
  for (int mt = 0; mt < 2; mt++)
#pragma unroll
    for (int nt = 0; nt < NT; nt++) {
      long row0 = bm + wm + mt * 16 + qd * 4;
      long col  = bn + wn + nt * 16 + c16;
      short4 p;
#pragma unroll
      for (int r = 0; r < 4; r++) {
        float v = acc[mt][nt][r];
        if constexpr (OUT_BF16) ((short*)Cout)[(row0 + r) * N + col] = f2bf(v);
        else                    ((float*)Cout)[(row0 + r) * N + col] = v;
        if constexpr (WRITE_VT)
          ((short*)&p)[r] = f2bf(v);
      }
      if constexpr (WRITE_VT) {
        if (col >= 1280) {                    // V section -> Vt[b*4+kvh][d][t]
          int d = (int)col - 1280;            // kvh = d>>6, dd = d&63
          int b = (int)(row0 >> 11), t = (int)(row0 & 2047);
          *(short4*)(&Vt[((long)(b * 256 + d)) * 2048 + t]) = p;
        }
      }
    }
}

// ---------- flash attention v8: BARRIER-FREE, register fragments ----------
// Key fact: K/V MFMA fragment addresses are pure functions of (lane, kt) —
// identical across the 4 waves of a block (same kvh) and across the 8 blocks
// sharing (b,kvh). So no LDS staging for K/V at all: per-lane global b128
// loads (L1 serves repeat waves; K+V per (b,kvh) = 768 KB, L2-resident).
// Only P needs LDS (cross-lane transpose) and it is PER-WAVE -> own-wave
// lgkmcnt(0) suffices. ZERO s_barrier in the K-loop; waves fully decoupled.
// Flat grid 1024. bx<512: qt = 127-(bx>>3); else (bx>>3)-64. Wave owns 16 q.
#define CSOFT 0.18033688f            // (1/sqrt(64)) * log2(e)
#define CMAX  (CSOFT * 12.0f)        // static shift; softmax shift-invariant

__global__ __launch_bounds__(256) void attn_kernel(const short* __restrict__ QKV,
                                                   const short* __restrict__ Vt,
                                                   short* __restrict__ Aout) {
  const int bx = blockIdx.x;
  const int qt = (bx < 512) ? (127 - (bx >> 3)) : ((bx >> 3) - 64);
  const int kvh = (bx >> 1) & 3, b = bx & 1;
  const int bkv = b * 4 + kvh;
  const int tid = threadIdx.x;
  const int w = tid >> 6, lane = tid & 63;
  const int qd = lane >> 4, c16 = lane & 15;
  const int h = kvh * 4 + w;
  const int q0 = qt * 16;

  __shared__ __attribute__((aligned(16))) short sP[4][16 * 72];   // per wave [q16][j64]

  // per-lane fragment pointers (bumped by constants each tile)
  // K A-frag: m=j=jc*16+c16 (row), k=d=qd*8+e (+32 for ks=1)
  const short* pK = QKV + ((long)(b * 2048 + c16)) * 1536 + 1024 + kvh * 64 + qd * 8;
  // V A-frag: m=d=dt*16+c16 (row of Vt), k=j=kt*64+ks2*32+qd*8+e
  const short* pV = Vt + ((long)(bkv * 64 + c16)) * 2048 + qd * 8;

  // Q fragments (B-operand: lane c16 = q, octet over d), from global once
  bf16x8 qf[2];
  {
    long tok = (long)b * 2048 + q0 + c16;
#pragma unroll
    for (int ks = 0; ks < 2; ks++)
      qf[ks] = *(const bf16x8*)(&QKV[tok * 1536 + h * 64 + ks * 32 + qd * 8]);
  }

  f32x4 Ot[4] = {};                 // O^T: row=d, col=q=c16 (un-normalized)
  float l_i = 0.f;                  // per-lane partial sum

  const int ntiles = (qt >> 2) + 1;
  for (int kt = 0; kt < ntiles; kt++) {
    // ---- K fragments for this tile: 8 per-lane global b128 loads ----
    bf16x8 kf[4][2];
#pragma unroll
    for (int jc = 0; jc < 4; jc++) {
      const short* p = pK + jc * (16 * 1536);
      kf[jc][0] = *(const bf16x8*)(p);
      kf[jc][1] = *(const bf16x8*)(p + 32);
    }
    // ---- V fragments half 0 (ks2=0) issued early; used after softmax ----
    bf16x8 vf0[4];
#pragma unroll
    for (int dt = 0; dt < 4; dt++)
      vf0[dt] = *(const bf16x8*)(pV + dt * (16 * 2048));

    // ---- S^T = K Q^T : A = K (c16 = j), B = Q (c16 = q) ----
    f32x4 St[4];
#pragma unroll
    for (int jc = 0; jc < 4; jc++) {
      f32x4 z = {};
      z = __builtin_amdgcn_mfma_f32_16x16x32_bf16(kf[jc][0], qf[0], z, 0, 0, 0);
      z = __builtin_amdgcn_mfma_f32_16x16x32_bf16(kf[jc][1], qf[1], z, 0, 0, 0);
      St[jc] = z;
    }

    // ---- causal mask on the diagonal (last) tile only ----
    if (kt == ntiles - 1) {
      int qg = q0 + c16 - kt * 64;            // q relative to tile
#pragma unroll
      for (int jc = 0; jc < 4; jc++)
#pragma unroll
        for (int r = 0; r < 4; r++)
          if (jc * 16 + qd * 4 + r > qg) St[jc][r] = -3e38f;
    }

    // ---- static-max softmax: p = exp2(CSOFT*s - CMAX); per-lane only ----
    {
      float rs = 0.f;
#pragma unroll
      for (int jc = 0; jc < 4; jc++) {
        unsigned u4[4];
#pragma unroll
        for (int r = 0; r < 4; r++) {
          float p = exp2f(fmaf(CSOFT, St[jc][r], -CMAX));
          u4[r] = __builtin_bit_cast(unsigned, p) & 0xffff0000u;  // truncate to bf16
          rs += __builtin_bit_cast(float, u4[r]);                 // l from truncated p
        }
        int2 pk;
        pk.x = (int)((u4[0] >> 16) | u4[1]);
        pk.y = (int)((u4[2] >> 16) | u4[3]);
        *(int2*)(&sP[w][c16 * 72 + jc * 16 + qd * 4]) = pk;
      }
      l_i += rs;
    }

    // ---- V fragments half 1 issued before the P wait (latency overlap) ----
    bf16x8 vf1[4];
#pragma unroll
    for (int dt = 0; dt < 4; dt++)
      vf1[dt] = *(const bf16x8*)(pV + dt * (16 * 2048) + 32);

    asm volatile("s_waitcnt lgkmcnt(0)" ::: "memory");  // own-wave sP retired
                                                        // (lockstep => all lanes')
    // ---- O^T += V^T P^T : A = Vt (c16 = d), B = P^T (c16 = q) ----
    bf16x8 pf0 = *(const bf16x8*)(&sP[w][c16 * 72 + 0 * 32 + qd * 8]);
    bf16x8 pf1 = *(const bf16x8*)(&sP[w][c16 * 72 + 1 * 32 + qd * 8]);
#pragma unroll
    for (int dt = 0; dt < 4; dt++)
      Ot[dt] = __builtin_amdgcn_mfma_f32_16x16x32_bf16(vf0[dt], pf0, Ot[dt], 0, 0, 0);
#pragma unroll
    for (int dt = 0; dt < 4; dt++)
      Ot[dt] = __builtin_amdgcn_mfma_f32_16x16x32_bf16(vf1[dt], pf1, Ot[dt], 0, 0, 0);

    pK += 64 * 1536;                 // next K tile
    pV += 64;                        // next V tile
  }

  // ---- epilogue: reduce l across the 4 qd groups, normalize, store O^T ----
  {
    float l = l_i;
    l += __shfl_xor(l, 16, 64);
    l += __shfl_xor(l, 32, 64);
    float inv = 1.f / l;
    long tok = (long)b * 2048 + q0 + c16;
#pragma unroll
    for (int dt = 0; dt < 4; dt++) {
      short4 o;
      o.x = f2bf(Ot[dt][0] * inv);
      o.y = f2bf(Ot[dt][1] * inv);
      o.z = f2bf(Ot[dt][2] * inv);
      o.w = f2bf(Ot[dt][3] * inv);
      *(short4*)(&Aout[tok * 1024 + h * 64 + dt * 16 + qd * 4]) = o;
    }
  }
}

// ---------- launch ----------
extern "C" void kernel_launch(void* const* d_in, const int* in_sizes, int n_in,
                              void* d_out, int out_size, void* d_ws, size_t ws_size,
                              hipStream_t stream) {
  const float* x   = (const float*)d_in[0];   // [2,2048,1024]
  const float* Wq  = (const float*)d_in[1];   // [1024,1024]
  const float* Wkv = (const float*)d_in[2];   // [1024,512]
  const float* Wo  = (const float*)d_in[3];   // [1024,1024]

  char* ws = (char*)d_ws;
  short* xb    = (short*)(ws);                          //  8,388,608 B
  short* Wqkvt = (short*)(ws + 8388608);                //  3,145,728 B  [1536][1024]
  short* Wot   = (short*)(ws + 11534336);               //  2,097,152 B  [1024][1024]
  short* QKV   = (short*)(ws + 13631488);               // 12,582,912 B  [4096][1536]
  short* attn  = (short*)(ws + 26214400);               //  8,388,608 B  [4096][1024]
  short* Vtb   = (short*)d_out;                         //  4,194,304 B scratch in d_out
                                                        //  (gemm2 overwrites ALL of d_out)

  // preprocessing: x->bf16 + weight transposes, one launch
  fused_pre<<<dim3(6656), 256, 0, stream>>>(x, Wq, Wkv, Wo, xb, Wqkvt, Wot);

  // QKV = xb @ Wqkv  (M=4096,N=1536,K=1024): 64x96 tiles, grid 1024, unrolled
  gemm_bt<1536, 1024, 3, true, true><<<dim3(16, 64), 256, 0, stream>>>(xb, Wqkvt, QKV, Vtb);

  // attention: 1024 blocks, barrier-free register-fragment design
  attn_kernel<<<dim3(1024), 256, 0, stream>>>(QKV, Vtb, attn);

  // out = attn @ Wo  (M=4096,N=1024,K=1024): 64x64 tiles, grid 1024, unrolled
  gemm_bt<1024, 1024, 2, false, false><<<dim3(16, 64), 256, 0, stream>>>(attn, Wot, d_out, nullptr);
}

// Round 12
// 204.849 us; speedup vs baseline: 1.1378x; 1.1378x over previous
//
#include <hip/hip_runtime.h>

// ---------- types ----------
using bf16x8 = __attribute__((ext_vector_type(8))) __bf16;
using f32x4  = __attribute__((ext_vector_type(4))) float;

__device__ __forceinline__ short f2bf(float f) {
  unsigned u = __builtin_bit_cast(unsigned, f);
  u += 0x7fffu + ((u >> 16) & 1u);   // RNE
  return (short)(u >> 16);
}

// async global->LDS, 16B per lane; lds base must be wave-uniform
__device__ __forceinline__ void gll16(const void* g, void* l) {
  __builtin_amdgcn_global_load_lds((const __attribute__((address_space(1))) unsigned*)g,
                                   (__attribute__((address_space(3))) unsigned*)l, 16, 0, 0);
}

// ---------- fused preprocessing: x->bf16 + all 3 weight transposes ----------
// grid 6656: [0,4096) convert x; [4096,5120) Wq; [5120,5632) Wkv; [5632,6656) Wo
__global__ __launch_bounds__(256) void fused_pre(const float* __restrict__ x,
                                                 const float* __restrict__ Wq,
                                                 const float* __restrict__ Wkv,
                                                 const float* __restrict__ Wo,
                                                 short* __restrict__ xb,
                                                 short* __restrict__ Wqkvt,
                                                 short* __restrict__ Wot) {
  const int bx = blockIdx.x, tid = threadIdx.x;
  if (bx < 4096) {
    int i = (bx * 256 + tid) * 4;
    float4 f = *(const float4*)(&x[i]);
    short4 o;
    o.x = f2bf(f.x); o.y = f2bf(f.y); o.z = f2bf(f.z); o.w = f2bf(f.w);
    *(short4*)(&xb[i]) = o;
    return;
  }
  __shared__ short tile[32][33];
  const float* src; short* dst; int C, ti;
  if (bx < 5120)      { src = Wq;  dst = Wqkvt;               C = 1024; ti = bx - 4096; }
  else if (bx < 5632) { src = Wkv; dst = Wqkvt + 1024 * 1024; C = 512;  ti = bx - 5120; }
  else                { src = Wo;  dst = Wot;                 C = 1024; ti = bx - 5632; }
  int ctiles = C >> 5;
  int c0 = (ti % ctiles) * 32, r0 = (ti / ctiles) * 32;
  int tx = tid & 31, ty = tid >> 5;
  for (int i = ty; i < 32; i += 8)
    tile[i][tx] = f2bf(src[(r0 + i) * C + c0 + tx]);
  __syncthreads();
  for (int i = ty; i < 32; i += 8)
    dst[(c0 + i) * 1024L + r0 + tx] = tile[tx][i];
}

// ---------- FLAT bf16 MFMA GEMM (AITER-flatmm style) ----------
// C[M][N] = A[M][K] * Bt[N][K]^T. ONE WAVE per block (64 thr), wave tile
// 64x64, K compile-time -> 16-iter loop FULLY unrolled, operands loaded
// DIRECTLY global->VGPR (b128 per lane, no LDS, no barriers, no fences) so
// the compiler software-pipelines loads across iterations with its own
// vmcnt tracking (the thing my manual fences kept defeating). 32 MFMA :
// 16 loads per iter. __launch_bounds__(64,2) caps VGPR at 256 (acc 64 +
// ~2-deep fragment pipeline).
// WRITE_VT: cols>=1280 (V section) also emit Vt[b][kvh][d][t].
template <int N, int K, bool OUT_BF16, bool WRITE_VT>
__global__ __launch_bounds__(64, 2) void flat_gemm(const short* __restrict__ A,
                                                   const short* __restrict__ Bt,
                                                   void* __restrict__ Cout,
                                                   short* __restrict__ Vt) {
  const int lane = threadIdx.x;
  const int bm = blockIdx.y * 64, bn = blockIdx.x * 64;
  const int qd = lane >> 4, c16 = lane & 15;

  f32x4 acc[4][4] = {};

  const short* pA = A  + (long)(bm + c16) * K + qd * 8;
  const short* pB = Bt + (long)(bn + c16) * K + qd * 8;

#pragma unroll
  for (int it = 0; it < (K >> 6); it++) {
    bf16x8 af[4][2], bfr[4][2];
#pragma unroll
    for (int t = 0; t < 4; t++)
#pragma unroll
      for (int ks = 0; ks < 2; ks++) {
        af[t][ks]  = *(const bf16x8*)(pA + (long)t * 16 * K + it * 64 + ks * 32);
        bfr[t][ks] = *(const bf16x8*)(pB + (long)t * 16 * K + it * 64 + ks * 32);
      }
#pragma unroll
    for (int ks = 0; ks < 2; ks++)
#pragma unroll
      for (int mt = 0; mt < 4; mt++)
#pragma unroll
        for (int nt = 0; nt < 4; nt++)
          acc[mt][nt] = __builtin_amdgcn_mfma_f32_16x16x32_bf16(af[mt][ks], bfr[nt][ks],
                                                                acc[mt][nt], 0, 0, 0);
  }

  // epilogue: C/D layout col=lane&15, row=(lane>>4)*4+reg  [m89-verified]
#pragma unroll
  for (int mt = 0; mt < 4; mt++)
#pragma unroll
    for (int nt = 0; nt < 4; nt++) {
      long row0 = bm + mt * 16 + qd * 4;
      long col  = bn + nt * 16 + c16;
      short4 p;
#pragma unroll
      for (int r = 0; r < 4; r++) {
        float v = acc[mt][nt][r];
        if constexpr (OUT_BF16) ((short*)Cout)[(row0 + r) * N + col] = f2bf(v);
        else                    ((float*)Cout)[(row0 + r) * N + col] = v;
        if constexpr (WRITE_VT)
          ((short*)&p)[r] = f2bf(v);
      }
      if constexpr (WRITE_VT) {
        if (col >= 1280) {                    // V section -> Vt[b*4+kvh][d][t]
          int d = (int)col - 1280;            // kvh = d>>6, dd = d&63
          int b = (int)(row0 >> 11), t = (int)(row0 & 2047);
          *(short4*)(&Vt[((long)(b * 256 + d)) * 2048 + t]) = p;
        }
      }
    }
}

// ---------- flash attention (R10 version, measured best ~42-44 us) ----------
// Flat grid 1024. bx<512: qt = 127-(bx>>3) (long, desc); else (bx>>3)-64.
// Block = 4 waves = 4 Q-heads of kv-group kvh; wave owns 16 q rows
// (q = lane&15), q0 = qt*16. S^T orientation, static-max softmax,
// sK dbuf / sVt single, incremental staging pointers.
#define CSOFT 0.18033688f            // (1/sqrt(64)) * log2(e)
#define CMAX  (CSOFT * 12.0f)        // static shift; softmax shift-invariant

__global__ __launch_bounds__(256, 4) void attn_kernel(const short* __restrict__ QKV,
                                                      const short* __restrict__ Vt,
                                                      short* __restrict__ Aout) {
  const int bx = blockIdx.x;
  const int qt = (bx < 512) ? (127 - (bx >> 3)) : ((bx >> 3) - 64);
  const int kvh = (bx >> 1) & 3, b = bx & 1;
  const int bkv = b * 4 + kvh;
  const int tid = threadIdx.x;
  const int w = tid >> 6, lane = tid & 63;
  const int qd = lane >> 4, c16 = lane & 15;
  const int h = kvh * 4 + w;
  const int q0 = qt * 16;

  // swizzled, stride 64 shorts: row r octet o at r*64 + (o ^ (r&7))*8
  __shared__ __attribute__((aligned(16))) short sK[2][64 * 64];    // [j][d] dbuf
  __shared__ __attribute__((aligned(16))) short sVt[64 * 64];      // [d][j] single
  __shared__ __attribute__((aligned(16))) short sP[4][16 * 72];    // per wave [q16][j64]

  // per-lane staging source pointers (bumped by constants each tile)
  const int r0 = tid >> 3, cc = tid & 7;
  const int sw = (cc ^ (r0 & 7)) * 8;
  const short* pK0 = QKV + ((long)(b * 2048 + r0)) * 1536 + 1024 + kvh * 64 + sw;
  const short* pK1 = pK0 + 32 * 1536;
  const short* pV0 = Vt + ((long)(bkv * 64 + r0)) * 2048 + sw;
  const short* pV1 = pV0 + 32 * 2048;
  short* const dK0[2] = { (short*)&sK[0][(w * 64) * 8],       (short*)&sK[1][(w * 64) * 8] };
  short* const dK1[2] = { (short*)&sK[0][(256 + w * 64) * 8], (short*)&sK[1][(256 + w * 64) * 8] };
  short* const dV0 = (short*)&sVt[(w * 64) * 8];
  short* const dV1 = (short*)&sVt[(256 + w * 64) * 8];

  auto stageK = [&](int d) {                 // stages the tile pK currently points at
    gll16(pK0, dK0[d]); gll16(pK1, dK1[d]);
    pK0 += 64 * 1536;   pK1 += 64 * 1536;
  };
  auto stageV = [&]() {
    gll16(pV0, dV0); gll16(pV1, dV1);
    pV0 += 64;       pV1 += 64;
  };

  stageK(0);                          // kt=0 in flight; pK -> kt=1

  // Q fragments (B-operand: lane c16 = q, octet over d), from global once
  bf16x8 qf[2];
  {
    long tok = (long)b * 2048 + q0 + c16;
#pragma unroll
    for (int ks = 0; ks < 2; ks++)
      qf[ks] = *(const bf16x8*)(&QKV[tok * 1536 + h * 64 + ks * 32 + qd * 8]);
  }

  f32x4 Ot[4] = {};                 // O^T: row=d, col=q=c16 (un-normalized)
  float l_i = 0.f;                  // per-lane partial sum

  const int ntiles = (qt >> 2) + 1;
  for (int kt = 0; kt < ntiles; kt++) {
    const int cur = kt & 1;
    asm volatile("" ::: "memory");
    __builtin_amdgcn_s_barrier();             // prev compute done: sVt & sK[cur^1] free
    stageV();                                 // 2 gll (waited before PV)
    if (kt + 1 < ntiles) {
      stageK(cur ^ 1);                        // 2 gll
      asm volatile("s_waitcnt vmcnt(4)" ::: "memory");  // prior K staging retired
    } else {
      asm volatile("s_waitcnt vmcnt(2)" ::: "memory");
    }
    __builtin_amdgcn_s_barrier();             // sK[cur] visible to all waves
    asm volatile("" ::: "memory");

    // ---- S^T = K Q^T : A = K (c16 = j), B = Q (c16 = q) ----
    f32x4 St[4];
#pragma unroll
    for (int jc = 0; jc < 4; jc++) {
      int rr = jc * 16 + c16;
      bf16x8 kf0 = *(const bf16x8*)(&sK[cur][rr * 64 + ((0 + qd) ^ (rr & 7)) * 8]);
      bf16x8 kf1 = *(const bf16x8*)(&sK[cur][rr * 64 + ((4 + qd) ^ (rr & 7)) * 8]);
      f32x4 z = {};
      z = __builtin_amdgcn_mfma_f32_16x16x32_bf16(kf0, qf[0], z, 0, 0, 0);
      z = __builtin_amdgcn_mfma_f32_16x16x32_bf16(kf1, qf[1], z, 0, 0, 0);
      St[jc] = z;
    }

    // ---- causal mask on the diagonal (last) tile only ----
    if (kt == ntiles - 1) {
      int qg = q0 + c16 - kt * 64;            // q relative to tile
#pragma unroll
      for (int jc = 0; jc < 4; jc++)
#pragma unroll
        for (int r = 0; r < 4; r++)
          if (jc * 16 + qd * 4 + r > qg) St[jc][r] = -3e38f;
    }

    // ---- static-max softmax: p = exp2(CSOFT*s - CMAX); per-lane only ----
    {
      float rs = 0.f;
#pragma unroll
      for (int jc = 0; jc < 4; jc++) {
        unsigned u4[4];
#pragma unroll
        for (int r = 0; r < 4; r++) {
          float p = exp2f(fmaf(CSOFT, St[jc][r], -CMAX));
          u4[r] = __builtin_bit_cast(unsigned, p) & 0xffff0000u;  // truncate to bf16
          rs += __builtin_bit_cast(float, u4[r]);                 // l from truncated p
        }
        int2 pk;
        pk.x = (int)((u4[0] >> 16) | u4[1]);
        pk.y = (int)((u4[2] >> 16) | u4[3]);
        *(int2*)(&sP[w][c16 * 72 + jc * 16 + qd * 4]) = pk;
      }
      l_i += rs;
    }
    asm volatile("s_waitcnt lgkmcnt(0)" ::: "memory");  // own sP writes retired

    // V tile arrived? (own gll) then barrier so ALL waves' chunks are in
    if (kt + 1 < ntiles) asm volatile("s_waitcnt vmcnt(2)" ::: "memory");
    else                 asm volatile("s_waitcnt vmcnt(0)" ::: "memory");
    __builtin_amdgcn_s_barrier();
    asm volatile("" ::: "memory");

    // ---- O^T += V^T P^T : A = Vt (c16 = d), B = P^T (c16 = q) ----
#pragma unroll
    for (int ks2 = 0; ks2 < 2; ks2++) {
      bf16x8 pf = *(const bf16x8*)(&sP[w][c16 * 72 + ks2 * 32 + qd * 8]);
#pragma unroll
      for (int dt = 0; dt < 4; dt++) {
        int rr = dt * 16 + c16;
        bf16x8 vf = *(const bf16x8*)(&sVt[rr * 64 + (((ks2 * 4 + qd) ^ (rr & 7)) * 8)]);
        Ot[dt] = __builtin_amdgcn_mfma_f32_16x16x32_bf16(vf, pf, Ot[dt], 0, 0, 0);
      }
    }
  }

  // ---- epilogue: reduce l across the 4 qd groups, normalize, store O^T ----
  {
    float l = l_i;
    l += __shfl_xor(l, 16, 64);
    l += __shfl_xor(l, 32, 64);
    float inv = 1.f / l;
    long tok = (long)b * 2048 + q0 + c16;
#pragma unroll
    for (int dt = 0; dt < 4; dt++) {
      short4 o;
      o.x = f2bf(Ot[dt][0] * inv);
      o.y = f2bf(Ot[dt][1] * inv);
      o.z = f2bf(Ot[dt][2] * inv);
      o.w = f2bf(Ot[dt][3] * inv);
      *(short4*)(&Aout[tok * 1024 + h * 64 + dt * 16 + qd * 4]) = o;
    }
  }
}

// ---------- launch ----------
extern "C" void kernel_launch(void* const* d_in, const int* in_sizes, int n_in,
                              void* d_out, int out_size, void* d_ws, size_t ws_size,
                              hipStream_t stream) {
  const float* x   = (const float*)d_in[0];   // [2,2048,1024]
  const float* Wq  = (const float*)d_in[1];   // [1024,1024]
  const float* Wkv = (const float*)d_in[2];   // [1024,512]
  const float* Wo  = (const float*)d_in[3];   // [1024,1024]

  char* ws = (char*)d_ws;
  short* xb    = (short*)(ws);                          //  8,388,608 B
  short* Wqkvt = (short*)(ws + 8388608);                //  3,145,728 B  [1536][1024]
  short* Wot   = (short*)(ws + 11534336);               //  2,097,152 B  [1024][1024]
  short* QKV   = (short*)(ws + 13631488);               // 12,582,912 B  [4096][1536]
  short* attn  = (short*)(ws + 26214400);               //  8,388,608 B  [4096][1024]
  short* Vtb   = (short*)d_out;                         //  4,194,304 B scratch in d_out
                                                        //  (gemm2 overwrites ALL of d_out)

  // preprocessing: x->bf16 + weight transposes, one launch
  fused_pre<<<dim3(6656), 256, 0, stream>>>(x, Wq, Wkv, Wo, xb, Wqkvt, Wot);

  // QKV = xb @ Wqkv  (M=4096,N=1536,K=1024): flat 64x64-per-wave, 1536 blocks
  flat_gemm<1536, 1024, true, true><<<dim3(24, 64), 64, 0, stream>>>(xb, Wqkvt, QKV, Vtb);

  // attention: 1024 blocks, two-phase qt order (measured best)
  attn_kernel<<<dim3(1024), 256, 0, stream>>>(QKV, Vtb, attn);

  // out = attn @ Wo  (M=4096,N=1024,K=1024): flat, 1024 blocks
  flat_gemm<1024, 1024, false, false><<<dim3(16, 64), 64, 0, stream>>>(attn, Wot, d_out, nullptr);
}

// Round 13
// 146.682 us; speedup vs baseline: 1.5891x; 1.3965x over previous
//
#include <hip/hip_runtime.h>

// ---------- types ----------
using bf16x8 = __attribute__((ext_vector_type(8))) __bf16;
using f32x4  = __attribute__((ext_vector_type(4))) float;

__device__ __forceinline__ short f2bf(float f) {
  unsigned u = __builtin_bit_cast(unsigned, f);
  u += 0x7fffu + ((u >> 16) & 1u);   // RNE
  return (short)(u >> 16);
}

// async global->LDS, 16B per lane; lds base must be wave-uniform
__device__ __forceinline__ void gll16(const void* g, void* l) {
  __builtin_amdgcn_global_load_lds((const __attribute__((address_space(1))) unsigned*)g,
                                   (__attribute__((address_space(3))) unsigned*)l, 16, 0, 0);
}

// ---------- fused preprocessing: x->bf16 + all 3 weight transposes ----------
// grid 6656: [0,4096) convert x; [4096,5120) Wq; [5120,5632) Wkv; [5632,6656) Wo
__global__ __launch_bounds__(256) void fused_pre(const float* __restrict__ x,
                                                 const float* __restrict__ Wq,
                                                 const float* __restrict__ Wkv,
                                                 const float* __restrict__ Wo,
                                                 short* __restrict__ xb,
                                                 short* __restrict__ Wqkvt,
                                                 short* __restrict__ Wot) {
  const int bx = blockIdx.x, tid = threadIdx.x;
  if (bx < 4096) {
    int i = (bx * 256 + tid) * 4;
    float4 f = *(const float4*)(&x[i]);
    short4 o;
    o.x = f2bf(f.x); o.y = f2bf(f.y); o.z = f2bf(f.z); o.w = f2bf(f.w);
    *(short4*)(&xb[i]) = o;
    return;
  }
  __shared__ short tile[32][33];
  const float* src; short* dst; int C, ti;
  if (bx < 5120)      { src = Wq;  dst = Wqkvt;               C = 1024; ti = bx - 4096; }
  else if (bx < 5632) { src = Wkv; dst = Wqkvt + 1024 * 1024; C = 512;  ti = bx - 5120; }
  else                { src = Wo;  dst = Wot;                 C = 1024; ti = bx - 5632; }
  int ctiles = C >> 5;
  int c0 = (ti % ctiles) * 32, r0 = (ti / ctiles) * 32;
  int tx = tid & 31, ty = tid >> 5;
  for (int i = ty; i < 32; i += 8)
    tile[i][tx] = f2bf(src[(r0 + i) * C + c0 + tx]);
  __syncthreads();
  for (int i = ty; i < 32; i += 8)
    dst[(c0 + i) * 1024L + r0 + tx] = tile[tx][i];
}

// ---------- bf16 MFMA GEMM: C[M][N] = A[M][K] * Bt[N][K]^T ----------
// R10 config (measured best) + two fixes:
//  (a) __launch_bounds__(256, 4): hard-cap 128 VGPR so 4 blocks/CU residency
//      is GUARANTEED (the unrolled dbuf loop could balloon VGPRs past 128 and
//      silently collapse the grid-1024 TLP design).
//  (b) flat-grid XCD swizzle: xcd=bx&7 owns 8 contiguous m-tiles x all 16
//      n-tiles -> per-XCD L2 keeps its A-slice + whole B resident.
// Block tile 64 x 32*NT, BK=64, dbuf gll16, XOR-swizzled LDS, grid 1024,
// compile-time N/K -> 16-iter loop fully unrolled.
template <int N, int K, int NT, bool OUT_BF16, bool WRITE_VT>
__global__ __launch_bounds__(256, 4) void gemm_bt(const short* __restrict__ A,
                                                  const short* __restrict__ Bt,
                                                  void* __restrict__ Cout,
                                                  short* __restrict__ Vt) {
  __shared__ __attribute__((aligned(16))) short sA[2][64 * 64];
  __shared__ __attribute__((aligned(16))) short sB[2][32 * NT * 64];
  const int tid  = threadIdx.x;
  const int bx   = blockIdx.x;
  const int xcd  = bx & 7, bi = bx >> 3;            // 1024 blocks: 8 xcd x 128
  const int bm   = (xcd * 8 + (bi >> 4)) * 64;      // 64 m-tiles, 8 per XCD
  const int bn   = (bi & 15) * (32 * NT);           // 16 n-tiles
  const int wave = tid >> 6, lane = tid & 63;
  const int wm = (wave >> 1) * 32, wn = (wave & 1) * (16 * NT);
  const int qd = lane >> 4, c16 = lane & 15;

  f32x4 acc[2][NT] = {};

  auto stage = [&](int it, int d) {
    int k0 = it * 64;
#pragma unroll
    for (int i = 0; i < 2; i++) {           // A: 64 rows x 8 octets
      int c = i * 256 + tid;
      int r = c >> 3, cc = c & 7;
      gll16(&A[(bm + r) * (long)K + k0 + ((cc ^ (r & 7)) * 8)],
            &sA[d][(i * 256 + wave * 64) * 8]);
    }
#pragma unroll
    for (int i = 0; i < NT; i++) {          // B: 32*NT rows x 8 octets
      int c = i * 256 + tid;
      int r = c >> 3, cc = c & 7;
      gll16(&Bt[(bn + r) * (long)K + k0 + ((cc ^ (r & 7)) * 8)],
            &sB[d][(i * 256 + wave * 64) * 8]);
    }
  };

  constexpr int niter = K >> 6;             // 16 — compile-time, fully unrolled
  stage(0, 0);
#pragma unroll
  for (int it = 0; it < niter; it++) {
    const int cur = it & 1;
    asm volatile("" ::: "memory");
    __builtin_amdgcn_s_barrier();            // buf[cur^1] free
    if (it + 1 < niter) {
      stage(it + 1, cur ^ 1);                // 2+NT gll16/thread
      if constexpr (NT == 3) asm volatile("s_waitcnt vmcnt(5)" ::: "memory");
      else                   asm volatile("s_waitcnt vmcnt(4)" ::: "memory");
    } else {
      asm volatile("s_waitcnt vmcnt(0)" ::: "memory");
    }
    __builtin_amdgcn_s_barrier();            // cur data visible
    asm volatile("" ::: "memory");

    bf16x8 af[2][2], bfr[NT][2];
#pragma unroll
    for (int mt = 0; mt < 2; mt++) {
      int rr = wm + mt * 16 + c16;
#pragma unroll
      for (int ks = 0; ks < 2; ks++)
        af[mt][ks] = *(const bf16x8*)(&sA[cur][rr * 64 + (((ks * 4 + qd) ^ (rr & 7)) * 8)]);
    }
#pragma unroll
    for (int nt = 0; nt < NT; nt++) {
      int rr = wn + nt * 16 + c16;
#pragma unroll
      for (int ks = 0; ks < 2; ks++)
        bfr[nt][ks] = *(const bf16x8*)(&sB[cur][rr * 64 + (((ks * 4 + qd) ^ (rr & 7)) * 8)]);
    }
#pragma unroll
    for (int ks = 0; ks < 2; ks++)
#pragma unroll
      for (int mt = 0; mt < 2; mt++)
#pragma unroll
        for (int nt = 0; nt < NT; nt++)
          acc[mt][nt] = __builtin_amdgcn_mfma_f32_16x16x32_bf16(af[mt][ks], bfr[nt][ks],
                                                                acc[mt][nt], 0, 0, 0);
  }

  // epilogue: C/D layout col=lane&15, row=(lane>>4)*4+reg  [m89-verified]
#pragma unroll
  for (int mt = 0; mt < 2; mt++)
#pragma unroll
    for (int nt = 0; nt < NT; nt++) {
      long row0 = bm + wm + mt * 16 + qd * 4;
      long col  = bn + wn + nt * 16 + c16;
      short4 p;
#pragma unroll
      for (int r = 0; r < 4; r++) {
        float v = acc[mt][nt][r];
        if constexpr (OUT_BF16) ((short*)Cout)[(row0 + r) * N + col] = f2bf(v);
        else                    ((float*)Cout)[(row0 + r) * N + col] = v;
        if constexpr (WRITE_VT)
          ((short*)&p)[r] = f2bf(v);
      }
      if constexpr (WRITE_VT) {
        if (col >= 1280) {                    // V section -> Vt[b*4+kvh][d][t]
          int d = (int)col - 1280;            // kvh = d>>6, dd = d&63
          int b = (int)(row0 >> 11), t = (int)(row0 & 2047);
          *(short4*)(&Vt[((long)(b * 256 + d)) * 2048 + t]) = p;
        }
      }
    }
}

// ---------- flash attention (R10 version, measured best) ----------
// Flat grid 1024. bx<512: qt = 127-(bx>>3) (long, desc); else (bx>>3)-64.
// Block = 4 waves = 4 Q-heads of kv-group kvh; wave owns 16 q rows
// (q = lane&15), q0 = qt*16. S^T orientation, static-max softmax,
// sK dbuf / sVt single, incremental staging pointers.
#define CSOFT 0.18033688f            // (1/sqrt(64)) * log2(e)
#define CMAX  (CSOFT * 12.0f)        // static shift; softmax shift-invariant

__global__ __launch_bounds__(256, 4) void attn_kernel(const short* __restrict__ QKV,
                                                      const short* __restrict__ Vt,
                                                      short* __restrict__ Aout) {
  const int bx = blockIdx.x;
  const int qt = (bx < 512) ? (127 - (bx >> 3)) : ((bx >> 3) - 64);
  const int kvh = (bx >> 1) & 3, b = bx & 1;
  const int bkv = b * 4 + kvh;
  const int tid = threadIdx.x;
  const int w = tid >> 6, lane = tid & 63;
  const int qd = lane >> 4, c16 = lane & 15;
  const int h = kvh * 4 + w;
  const int q0 = qt * 16;

  // swizzled, stride 64 shorts: row r octet o at r*64 + (o ^ (r&7))*8
  __shared__ __attribute__((aligned(16))) short sK[2][64 * 64];    // [j][d] dbuf
  __shared__ __attribute__((aligned(16))) short sVt[64 * 64];      // [d][j] single
  __shared__ __attribute__((aligned(16))) short sP[4][16 * 72];    // per wave [q16][j64]

  // per-lane staging source pointers (bumped by constants each tile)
  const int r0 = tid >> 3, cc = tid & 7;
  const int sw = (cc ^ (r0 & 7)) * 8;
  const short* pK0 = QKV + ((long)(b * 2048 + r0)) * 1536 + 1024 + kvh * 64 + sw;
  const short* pK1 = pK0 + 32 * 1536;
  const short* pV0 = Vt + ((long)(bkv * 64 + r0)) * 2048 + sw;
  const short* pV1 = pV0 + 32 * 2048;
  short* const dK0[2] = { (short*)&sK[0][(w * 64) * 8],       (short*)&sK[1][(w * 64) * 8] };
  short* const dK1[2] = { (short*)&sK[0][(256 + w * 64) * 8], (short*)&sK[1][(256 + w * 64) * 8] };
  short* const dV0 = (short*)&sVt[(w * 64) * 8];
  short* const dV1 = (short*)&sVt[(256 + w * 64) * 8];

  auto stageK = [&](int d) {                 // stages the tile pK currently points at
    gll16(pK0, dK0[d]); gll16(pK1, dK1[d]);
    pK0 += 64 * 1536;   pK1 += 64 * 1536;
  };
  auto stageV = [&]() {
    gll16(pV0, dV0); gll16(pV1, dV1);
    pV0 += 64;       pV1 += 64;
  };

  stageK(0);                          // kt=0 in flight; pK -> kt=1

  // Q fragments (B-operand: lane c16 = q, octet over d), from global once
  bf16x8 qf[2];
  {
    long tok = (long)b * 2048 + q0 + c16;
#pragma unroll
    for (int ks = 0; ks < 2; ks++)
      qf[ks] = *(const bf16x8*)(&QKV[tok * 1536 + h * 64 + ks * 32 + qd * 8]);
  }

  f32x4 Ot[4] = {};                 // O^T: row=d, col=q=c16 (un-normalized)
  float l_i = 0.f;                  // per-lane partial sum

  const int ntiles = (qt >> 2) + 1;
  for (int kt = 0; kt < ntiles; kt++) {
    const int cur = kt & 1;
    asm volatile("" ::: "memory");
    __builtin_amdgcn_s_barrier();             // prev compute done: sVt & sK[cur^1] free
    stageV();                                 // 2 gll (waited before PV)
    if (kt + 1 < ntiles) {
      stageK(cur ^ 1);                        // 2 gll
      asm volatile("s_waitcnt vmcnt(4)" ::: "memory");  // prior K staging retired
    } else {
      asm volatile("s_waitcnt vmcnt(2)" ::: "memory");
    }
    __builtin_amdgcn_s_barrier();             // sK[cur] visible to all waves
    asm volatile("" ::: "memory");

    // ---- S^T = K Q^T : A = K (c16 = j), B = Q (c16 = q) ----
    f32x4 St[4];
#pragma unroll
    for (int jc = 0; jc < 4; jc++) {
      int rr = jc * 16 + c16;
      bf16x8 kf0 = *(const bf16x8*)(&sK[cur][rr * 64 + ((0 + qd) ^ (rr & 7)) * 8]);
      bf16x8 kf1 = *(const bf16x8*)(&sK[cur][rr * 64 + ((4 + qd) ^ (rr & 7)) * 8]);
      f32x4 z = {};
      z = __builtin_amdgcn_mfma_f32_16x16x32_bf16(kf0, qf[0], z, 0, 0, 0);
      z = __builtin_amdgcn_mfma_f32_16x16x32_bf16(kf1, qf[1], z, 0, 0, 0);
      St[jc] = z;
    }

    // ---- causal mask on the diagonal (last) tile only ----
    if (kt == ntiles - 1) {
      int qg = q0 + c16 - kt * 64;            // q relative to tile
#pragma unroll
      for (int jc = 0; jc < 4; jc++)
#pragma unroll
        for (int r = 0; r < 4; r++)
          if (jc * 16 + qd * 4 + r > qg) St[jc][r] = -3e38f;
    }

    // ---- static-max softmax: p = exp2(CSOFT*s - CMAX); per-lane only ----
    {
      float rs = 0.f;
#pragma unroll
      for (int jc = 0; jc < 4; jc++) {
        unsigned u4[4];
#pragma unroll
        for (int r = 0; r < 4; r++) {
          float p = exp2f(fmaf(CSOFT, St[jc][r], -CMAX));
          u4[r] = __builtin_bit_cast(unsigned, p) & 0xffff0000u;  // truncate to bf16
          rs += __builtin_bit_cast(float, u4[r]);                 // l from truncated p
        }
        int2 pk;
        pk.x = (int)((u4[0] >> 16) | u4[1]);
        pk.y = (int)((u4[2] >> 16) | u4[3]);
        *(int2*)(&sP[w][c16 * 72 + jc * 16 + qd * 4]) = pk;
      }
      l_i += rs;
    }
    asm volatile("s_waitcnt lgkmcnt(0)" ::: "memory");  // own sP writes retired

    // V tile arrived? (own gll) then barrier so ALL waves' chunks are in
    if (kt + 1 < ntiles) asm volatile("s_waitcnt vmcnt(2)" ::: "memory");
    else                 asm volatile("s_waitcnt vmcnt(0)" ::: "memory");
    __builtin_amdgcn_s_barrier();
    asm volatile("" ::: "memory");

    // ---- O^T += V^T P^T : A = Vt (c16 = d), B = P^T (c16 = q) ----
#pragma unroll
    for (int ks2 = 0; ks2 < 2; ks2++) {
      bf16x8 pf = *(const bf16x8*)(&sP[w][c16 * 72 + ks2 * 32 + qd * 8]);
#pragma unroll
      for (int dt = 0; dt < 4; dt++) {
        int rr = dt * 16 + c16;
        bf16x8 vf = *(const bf16x8*)(&sVt[rr * 64 + (((ks2 * 4 + qd) ^ (rr & 7)) * 8)]);
        Ot[dt] = __builtin_amdgcn_mfma_f32_16x16x32_bf16(vf, pf, Ot[dt], 0, 0, 0);
      }
    }
  }

  // ---- epilogue: reduce l across the 4 qd groups, normalize, store O^T ----
  {
    float l = l_i;
    l += __shfl_xor(l, 16, 64);
    l += __shfl_xor(l, 32, 64);
    float inv = 1.f / l;
    long tok = (long)b * 2048 + q0 + c16;
#pragma unroll
    for (int dt = 0; dt < 4; dt++) {
      short4 o;
      o.x = f2bf(Ot[dt][0] * inv);
      o.y = f2bf(Ot[dt][1] * inv);
      o.z = f2bf(Ot[dt][2] * inv);
      o.w = f2bf(Ot[dt][3] * inv);
      *(short4*)(&Aout[tok * 1024 + h * 64 + dt * 16 + qd * 4]) = o;
    }
  }
}

// ---------- launch ----------
extern "C" void kernel_launch(void* const* d_in, const int* in_sizes, int n_in,
                              void* d_out, int out_size, void* d_ws, size_t ws_size,
                              hipStream_t stream) {
  const float* x   = (const float*)d_in[0];   // [2,2048,1024]
  const float* Wq  = (const float*)d_in[1];   // [1024,1024]
  const float* Wkv = (const float*)d_in[2];   // [1024,512]
  const float* Wo  = (const float*)d_in[3];   // [1024,1024]

  char* ws = (char*)d_ws;
  short* xb    = (short*)(ws);                          //  8,388,608 B
  short* Wqkvt = (short*)(ws + 8388608);                //  3,145,728 B  [1536][1024]
  short* Wot   = (short*)(ws + 11534336);               //  2,097,152 B  [1024][1024]
  short* QKV   = (short*)(ws + 13631488);               // 12,582,912 B  [4096][1536]
  short* attn  = (short*)(ws + 26214400);               //  8,388,608 B  [4096][1024]
  short* Vtb   = (short*)d_out;                         //  4,194,304 B scratch in d_out
                                                        //  (gemm2 overwrites ALL of d_out)

  // preprocessing: x->bf16 + weight transposes, one launch
  fused_pre<<<dim3(6656), 256, 0, stream>>>(x, Wq, Wkv, Wo, xb, Wqkvt, Wot);

  // QKV = xb @ Wqkv  (M=4096,N=1536,K=1024): 64x96 tiles, grid 1024, XCD-swizzled
  gemm_bt<1536, 1024, 3, true, true><<<dim3(1024), 256, 0, stream>>>(xb, Wqkvt, QKV, Vtb);

  // attention: 1024 blocks, two-phase qt order (measured best)
  attn_kernel<<<dim3(1024), 256, 0, stream>>>(QKV, Vtb, attn);

  // out = attn @ Wo  (M=4096,N=1024,K=1024): 64x64 tiles, grid 1024, XCD-swizzled
  gemm_bt<1024, 1024, 2, false, false><<<dim3(1024), 256, 0, stream>>>(attn, Wot, d_out, nullptr);
}